// Round 6
// baseline (1213.843 us; speedup 1.0000x reference)
//
#include <hip/hip_runtime.h>
#include <hip/hip_bf16.h>

#define Df 384
#define Hf 768
#define SCAN_CH 4096

typedef __bf16 bf16x8 __attribute__((ext_vector_type(8)));
typedef float f32x4 __attribute__((ext_vector_type(4)));

struct __attribute__((aligned(4))) U12 { unsigned int x, y, z; };

__device__ inline unsigned short f2bf(float f) {
    __hip_bfloat16 h = __float2bfloat16(f);
    return __builtin_bit_cast(unsigned short, h);
}
__device__ inline float bf2f(unsigned short u) {
    unsigned int v = ((unsigned int)u) << 16;
    return __builtin_bit_cast(float, v);
}
__device__ inline float lobf(unsigned int v) { return bf2f((unsigned short)(v & 0xffff)); }
__device__ inline float hibf(unsigned int v) { return bf2f((unsigned short)(v >> 16)); }
__device__ inline unsigned int pk2(float a, float b) {
    return (unsigned int)f2bf(a) | ((unsigned int)f2bf(b) << 16);
}
__device__ inline float gelu_(float v) {
    return 0.5f * v * (1.0f + erff(v * 0.70710678118654752f));
}
// direct global->LDS, 16B per lane; LDS dest is wave-uniform base + lane*16,
// global source address is PER-LANE (used for the read-swizzle inverse).
__device__ inline void gload16(const void* g, void* l) {
    __builtin_amdgcn_global_load_lds(
        (const __attribute__((address_space(1))) unsigned int*)g,
        (__attribute__((address_space(3))) unsigned int*)l, 16, 0, 0);
}

// ---- BN column statistics: sum + sumsq per feature ----
__global__ void bn_stats(const float* __restrict__ x, float* __restrict__ stats, int N) {
    int t = threadIdx.x;                 // 192 threads
    int c4 = (t % 96) * 4;
    int rs = t / 96;
    float s0 = 0, s1 = 0, s2 = 0, s3 = 0, q0 = 0, q1 = 0, q2 = 0, q3 = 0;
    for (int r = blockIdx.x * 2 + rs; r < N; r += gridDim.x * 2) {
        float4 v = *(const float4*)(x + (size_t)r * Df + c4);
        s0 += v.x; s1 += v.y; s2 += v.z; s3 += v.w;
        q0 += v.x * v.x; q1 += v.y * v.y; q2 += v.z * v.z; q3 += v.w * v.w;
    }
    unsafeAtomicAdd(&stats[c4 + 0], s0);
    unsafeAtomicAdd(&stats[c4 + 1], s1);
    unsafeAtomicAdd(&stats[c4 + 2], s2);
    unsafeAtomicAdd(&stats[c4 + 3], s3);
    unsafeAtomicAdd(&stats[Df + c4 + 0], q0);
    unsafeAtomicAdd(&stats[Df + c4 + 1], q1);
    unsafeAtomicAdd(&stats[Df + c4 + 2], q2);
    unsafeAtomicAdd(&stats[Df + c4 + 3], q3);
}

__global__ void bn_finalize(const float* __restrict__ stats,
                            const float* __restrict__ gamma,
                            const float* __restrict__ beta,
                            float* __restrict__ coef, int N) {
    int c = threadIdx.x; // 384
    float invN = 1.0f / (float)N;
    float mu = stats[c] * invN;
    float var = stats[Df + c] * invN - mu * mu;
    float rs = rsqrtf(var + 1e-5f);
    float a = gamma[c] * rs;
    coef[c] = a;
    coef[Df + c] = beta[c] - mu * a;
}

// ---- h = x*a + b  ->  bf16 ----
__global__ void h_kernel(const float* __restrict__ x, const float* __restrict__ coef,
                         unsigned short* __restrict__ hb, int tot8) {
    int i = blockIdx.x * 256 + threadIdx.x;
    if (i >= tot8) return;
    size_t base = (size_t)i * 8;
    int c = (int)(base % Df);
    float4 x0 = *(const float4*)(x + base);
    float4 x1 = *(const float4*)(x + base + 4);
    const float* a = coef + c;
    const float* b = coef + Df + c;
    uint4 o;
    o.x = pk2(x0.x * a[0] + b[0], x0.y * a[1] + b[1]);
    o.y = pk2(x0.z * a[2] + b[2], x0.w * a[3] + b[3]);
    o.z = pk2(x1.x * a[4] + b[4], x1.y * a[5] + b[5]);
    o.w = pk2(x1.z * a[6] + b[6], x1.w * a[7] + b[7]);
    *(uint4*)(hb + base) = o;
}

// ---- weight transpose + cast: W[K][Nc] f32 -> Wt[Nc][K] bf16 ----
__global__ void wtrans(const float* __restrict__ Wsrc, unsigned short* __restrict__ Wdst,
                       int K, int Nc) {
    int idx = blockIdx.x * 256 + threadIdx.x;
    if (idx >= K * Nc) return;
    int k = idx / Nc, n = idx % Nc;
    Wdst[(size_t)n * K + k] = f2bf(Wsrc[idx]);
}

// ---- CSR build ----
__global__ void degree_k(const int* __restrict__ dst, int* __restrict__ deg, int E) {
    int e = blockIdx.x * 256 + threadIdx.x;
    if (e < E) atomicAdd(&deg[dst[e]], 1);
}

__global__ void scan1(const int* __restrict__ deg, int* __restrict__ off,
                      int* __restrict__ sums, int N) {
    __shared__ int ts[256];
    int t = threadIdx.x;
    int base = blockIdx.x * SCAN_CH + t * 16;
    int v[16];
    int s = 0;
    for (int j = 0; j < 16; j++) {
        int idx = base + j;
        int d = (idx < N) ? deg[idx] : 0;
        v[j] = s;
        s += d;
    }
    ts[t] = s;
    __syncthreads();
    for (int o = 1; o < 256; o <<= 1) {
        int add = (t >= o) ? ts[t - o] : 0;
        __syncthreads();
        ts[t] += add;
        __syncthreads();
    }
    int pre = t ? ts[t - 1] : 0;
    for (int j = 0; j < 16; j++) {
        int idx = base + j;
        if (idx < N) off[idx] = pre + v[j];
    }
    if (t == 255) sums[blockIdx.x] = ts[255];
}

__global__ void scan2(int* __restrict__ sums, int nb) {
    int acc = 0;
    for (int b = 0; b < nb; b++) { int v = sums[b]; sums[b] = acc; acc += v; }
    sums[nb] = acc;
}

__global__ void scan3(int* __restrict__ off, const int* __restrict__ sums, int N, int nb) {
    int idx = blockIdx.x * 256 + threadIdx.x;
    if (idx < N) off[idx] += sums[idx / SCAN_CH];
    else if (idx == N) off[N] = sums[nb];
}

// fill: pose[e] = CSR slot of edge e; srcp[slot] = src node of that edge
__global__ void fill_k(const int* __restrict__ dst, const int* __restrict__ src,
                       int* __restrict__ cursor, int* __restrict__ srcp,
                       int* __restrict__ pose, int E) {
    int e = blockIdx.x * 256 + threadIdx.x;
    if (e >= E) return;
    int pos = atomicAdd(&cursor[dst[e]], 1);
    srcp[pos] = src[e];
    pose[e] = pos;
}

// ---- gather-reduce: z[i] = (1+eps)*h[i] + sum_{p in [off[i],off[i+1])} relu(msgl[p] + h[srcp[p]]) ----
__global__ __launch_bounds__(256) void aggregate(
    const unsigned short* __restrict__ msgl, const unsigned short* __restrict__ hb,
    const int* __restrict__ off, const int* __restrict__ srcp,
    const float* __restrict__ epsp,
    unsigned short* __restrict__ zb, int N) {
    int lane = threadIdx.x & 63;
    int wid = threadIdx.x >> 6;
    int nwaves = gridDim.x * 4;
    float s1p = 1.0f + epsp[0];
    int loff = lane * 6;
    for (int i = blockIdx.x * 4 + wid; i < N; i += nwaves) {
        int o0 = off[i], o1 = off[i + 1];
        float a0 = 0, a1 = 0, a2 = 0, a3 = 0, a4 = 0, a5 = 0;
        for (int p = o0; p < o1; ++p) {
            int s = srcp[p];
            U12 mv = *(const U12*)(msgl + (size_t)p * Df + loff);
            U12 hv = *(const U12*)(hb + (size_t)s * Df + loff);
            a0 += fmaxf(lobf(mv.x) + lobf(hv.x), 0.f);
            a1 += fmaxf(hibf(mv.x) + hibf(hv.x), 0.f);
            a2 += fmaxf(lobf(mv.y) + lobf(hv.y), 0.f);
            a3 += fmaxf(hibf(mv.y) + hibf(hv.y), 0.f);
            a4 += fmaxf(lobf(mv.z) + lobf(hv.z), 0.f);
            a5 += fmaxf(hibf(mv.z) + hibf(hv.z), 0.f);
        }
        U12 hv = *(const U12*)(hb + (size_t)i * Df + loff);
        U12 o;
        o.x = pk2(s1p * lobf(hv.x) + a0, s1p * hibf(hv.x) + a1);
        o.y = pk2(s1p * lobf(hv.y) + a2, s1p * hibf(hv.y) + a3);
        o.z = pk2(s1p * lobf(hv.z) + a4, s1p * hibf(hv.z) + a5);
        *(U12*)(zb + (size_t)i * Df + loff) = o;
    }
}

// ---- B-resident GEMM: C = A @ Bt^T (+bias + epilogue) ----
// Block = 256 rows x 64 cols, 4 waves (each wave 64 rows x 64 cols).
// B panel resident in LDS, loaded once per 384-k chunk via per-lane-swizzled
// global_load_lds source (swizzle is its own inverse on the read side).
// A-fragments stream global->registers (16B/lane contiguous), depth-D
// prefetch, NO barriers in the K-loop.
// EPI 1: out = bf16(gelu(acc + bias))
// EPI 2: out = xres + gelu(acc + bias)   (f32)
// EPI 3: out row permuted via pose: outb[pose[row]] = bf16(acc + bias)
template <int NTK, int EPI, bool ABF16>
__global__ __launch_bounds__(256, 3) void gemm2(
    const void* __restrict__ Ap, const unsigned short* __restrict__ Bt,
    const float* __restrict__ bias, int M, int ncols,
    const int* __restrict__ pose,
    unsigned short* __restrict__ outb,
    const float* __restrict__ xres, float* __restrict__ outf, int ldo) {
    constexpr int K = NTK * 32;
    constexpr int NCH = (NTK + 11) / 12;   // 384-k chunks
    constexpr int CKT = NTK / NCH;         // kt per chunk (12)
    constexpr int D = ABF16 ? 3 : 2;       // A prefetch depth
    constexpr int PW = ABF16 ? 4 : 8;      // uint4 per prefetch stage
    __shared__ __align__(16) unsigned short Bs[CKT * 64 * 32];

    const int t = threadIdx.x;
    // m204 bijective XCD swizzle, col-block fastest within an XCD chunk
    const int nwg = gridDim.x;
    const int orig = blockIdx.x;
    const int xcd = orig & 7;
    const int q = nwg >> 3, r = nwg & 7;
    const int wgid = (xcd < r ? xcd * (q + 1) : r * (q + 1) + (xcd - r) * q) + (orig >> 3);
    const int pp = wgid / ncols;
    const int m0 = pp * 256;
    const int n0 = (wgid - pp * ncols) * 64;

    const int lane = t & 63;
    const int wid = t >> 6;
    const int fr = lane & 15;
    const int kg = lane >> 4;
    const int crow = lane >> 2;   // B-staging row within 16-row group
    const int cseg = lane & 3;    // B-staging 16B segment
    const int ssw = (crow >> 1) & 3;       // staging source swizzle
    const int bseg = kg ^ ((fr >> 1) & 3); // read-side swizzle (inverse of ssw)

    f32x4 acc[4][4];
#pragma unroll
    for (int i = 0; i < 4; i++)
#pragma unroll
        for (int j = 0; j < 4; j++) acc[i][j] = (f32x4){0.f, 0.f, 0.f, 0.f};

    int arow[4];
#pragma unroll
    for (int i = 0; i < 4; i++) {
        int rr = m0 + wid * 64 + i * 16 + fr;
        arow[i] = rr < M ? rr : M - 1;
    }

    auto stageB = [&](int ch) {
        const int ktw = wid * 3;
#pragma unroll
        for (int c = 0; c < 3; c++) {
#pragma unroll
            for (int rb = 0; rb < 64; rb += 16) {
                const int col = n0 + rb + crow;
                const int kk = (ch * CKT + ktw + c) * 32 + ((cseg ^ ssw) << 3);
                gload16(Bt + (size_t)col * K + kk,
                        &Bs[((ktw + c) * 64 + rb) * 32]);
            }
        }
    };
    auto issueA = [&](int kt, uint4* dst) {
#pragma unroll
        for (int i = 0; i < 4; i++) {
            if (ABF16) {
                dst[i] = *(const uint4*)((const unsigned short*)Ap +
                                         (size_t)arow[i] * K + kt * 32 + kg * 8);
            } else {
                const float* p = (const float*)Ap + (size_t)arow[i] * K + kt * 32 + kg * 8;
                dst[2 * i] = *(const uint4*)p;
                dst[2 * i + 1] = *(const uint4*)(p + 4);
            }
        }
    };
    auto toFrag = [&](const uint4* src, bf16x8* a) {
#pragma unroll
        for (int i = 0; i < 4; i++) {
            if (ABF16) {
                a[i] = __builtin_bit_cast(bf16x8, src[i]);
            } else {
                float4 x0 = __builtin_bit_cast(float4, src[2 * i]);
                float4 x1 = __builtin_bit_cast(float4, src[2 * i + 1]);
                uint4 u;
                u.x = pk2(x0.x, x0.y); u.y = pk2(x0.z, x0.w);
                u.z = pk2(x1.x, x1.y); u.w = pk2(x1.z, x1.w);
                a[i] = __builtin_bit_cast(bf16x8, u);
            }
        }
    };

    uint4 pf[D][PW];
    stageB(0);
#pragma unroll
    for (int d = 0; d < D; d++)          // fill ALL D prefetch stages (R5 bug: only 2 of 3)
        issueA(d < NTK ? d : NTK - 1, pf[d]);
    __syncthreads();   // B chunk 0 ready (vmcnt drain)

#pragma unroll
    for (int ch = 0; ch < NCH; ch++) {
        if (ch > 0) {
            __syncthreads();      // everyone done reading previous chunk
            stageB(ch);
            __syncthreads();      // new chunk ready
        }
#pragma unroll
        for (int k = 0; k < CKT; k++) {
            const int kt = ch * CKT + k;
            bf16x8 b[4];
#pragma unroll
            for (int j = 0; j < 4; j++)
                b[j] = *(const bf16x8*)((const char*)Bs +
                                        ((k * 64 + j * 16 + fr) * 64 + bseg * 16));
            bf16x8 a[4];
            toFrag(pf[kt % D], a);
            if (kt + D < NTK) issueA(kt + D, pf[(kt + D) % D]);
#pragma unroll
            for (int i = 0; i < 4; i++)
#pragma unroll
                for (int j = 0; j < 4; j++)
                    acc[i][j] = __builtin_amdgcn_mfma_f32_16x16x32_bf16(a[i], b[j], acc[i][j], 0, 0, 0);
        }
    }

    float bi[4];
#pragma unroll
    for (int j = 0; j < 4; j++) bi[j] = bias[n0 + j * 16 + fr];

    const int kg4 = kg * 4;
#pragma unroll
    for (int i = 0; i < 4; i++) {
        const int rb = m0 + wid * 64 + i * 16 + kg4;
#pragma unroll
        for (int j = 0; j < 4; j++) {
            const int c = n0 + j * 16 + fr;
#pragma unroll
            for (int r = 0; r < 4; r++) {
                const int row = rb + r;
                if (row < M) {
                    float v = acc[i][j][r] + bi[j];
                    if (EPI == 1) {
                        outb[(size_t)row * ldo + c] = f2bf(gelu_(v));
                    } else if (EPI == 2) {
                        size_t o = (size_t)row * ldo + c;
                        outf[o] = xres[o] + gelu_(v);
                    } else {
                        outb[(size_t)pose[row] * ldo + c] = f2bf(v);
                    }
                }
            }
        }
    }
}

extern "C" void kernel_launch(void* const* d_in, const int* in_sizes, int n_in,
                              void* d_out, int out_size, void* d_ws, size_t ws_size,
                              hipStream_t stream) {
    const float* x = (const float*)d_in[0];
    const float* ea = (const float*)d_in[1];
    const float* gamma = (const float*)d_in[2];
    const float* beta = (const float*)d_in[3];
    const float* epsp = (const float*)d_in[4];
    const float* W_edge = (const float*)d_in[5];
    const float* b_edge = (const float*)d_in[6];
    const float* W1 = (const float*)d_in[7];
    const float* b1 = (const float*)d_in[8];
    const float* W2 = (const float*)d_in[9];
    const float* b2 = (const float*)d_in[10];
    const int* eidx = (const int*)d_in[11];
    float* out = (float*)d_out;
    const int N = in_sizes[0] / Df;
    const int E = in_sizes[1] / Df;
    const int* esrc = eidx;
    const int* edst = eidx + E;

    char* w = (char*)d_ws;
    size_t off_ = 0;
    auto alloc = [&](size_t bytes) { char* p = w + off_; off_ += (bytes + 255) & ~(size_t)255; return p; };
    float* stats = (float*)alloc(2 * Df * sizeof(float));
    float* coef = (float*)alloc(2 * Df * sizeof(float));
    unsigned short* hb = (unsigned short*)alloc((size_t)N * Df * 2);
    unsigned short* zb = (unsigned short*)alloc((size_t)N * Df * 2);
    unsigned short* tb = (unsigned short*)alloc((size_t)N * Hf * 2);
    unsigned short* WeT = (unsigned short*)alloc((size_t)Df * Df * 2);
    unsigned short* W1T = (unsigned short*)alloc((size_t)Df * Hf * 2);
    unsigned short* W2T = (unsigned short*)alloc((size_t)Hf * Df * 2);
    int* deg = (int*)alloc((size_t)(N + 1) * 4);      // reused as fill cursor
    int* offs = (int*)alloc((size_t)(N + 1) * 4);
    int* srcp = (int*)alloc((size_t)E * 4);
    int* pose = (int*)alloc((size_t)E * 4);
    int* sums = (int*)alloc(64 * 4);
    size_t msgl_bytes = (size_t)E * Df * 2;
    unsigned short* msgl;
    if (off_ + msgl_bytes <= ws_size) msgl = (unsigned short*)alloc(msgl_bytes);
    else msgl = (unsigned short*)d_out;   // dead until final GEMM writes it
    (void)n_in; (void)out_size;

    hipMemsetAsync(stats, 0, 2 * Df * sizeof(float), stream);
    hipMemsetAsync(deg, 0, (size_t)N * 4, stream);

    // BN + h
    bn_stats<<<1024, 192, 0, stream>>>(x, stats, N);
    bn_finalize<<<1, Df, 0, stream>>>(stats, gamma, beta, coef, N);
    int tot8 = N * Df / 8;
    h_kernel<<<(tot8 + 255) / 256, 256, 0, stream>>>(x, coef, hb, tot8);

    // weights
    wtrans<<<(Df * Df + 255) / 256, 256, 0, stream>>>(W_edge, WeT, Df, Df);
    wtrans<<<(Df * Hf + 255) / 256, 256, 0, stream>>>(W1, W1T, Df, Hf);
    wtrans<<<(Hf * Df + 255) / 256, 256, 0, stream>>>(W2, W2T, Hf, Df);

    // CSR by dst
    int nb = (N + SCAN_CH - 1) / SCAN_CH;
    degree_k<<<(E + 255) / 256, 256, 0, stream>>>(edst, deg, E);
    scan1<<<nb, 256, 0, stream>>>(deg, offs, sums, N);
    scan2<<<1, 1, 0, stream>>>(sums, nb);
    scan3<<<(N + 256) / 256, 256, 0, stream>>>(offs, sums, N, nb);
    hipMemcpyAsync(deg, offs, (size_t)N * 4, hipMemcpyDeviceToDevice, stream);
    fill_k<<<(E + 255) / 256, 256, 0, stream>>>(edst, esrc, deg, srcp, pose, E);

    // edge linear: msgl[pose[e]] = ea[e] @ We^T + b_edge  (bf16, CSR-ordered)
    int ep2 = (E + 255) / 256;
    gemm2<12, 3, false><<<dim3(ep2 * (Df / 64)), 256, 0, stream>>>(
        ea, WeT, b_edge, E, Df / 64, pose, msgl, nullptr, nullptr, Df);

    // gather-reduce -> z (bf16)
    aggregate<<<2048, 256, 0, stream>>>(msgl, hb, offs, srcp, epsp, zb, N);

    // MLP
    int np2 = (N + 255) / 256;
    gemm2<12, 1, true><<<dim3(np2 * (Hf / 64)), 256, 0, stream>>>(
        zb, W1T, b1, N, Hf / 64, nullptr, tb, nullptr, nullptr, Hf);
    gemm2<24, 2, true><<<dim3(np2 * (Df / 64)), 256, 0, stream>>>(
        tb, W2T, b2, N, Df / 64, nullptr, nullptr, x, out, Df);
}

// Round 7
// 1212.229 us; speedup vs baseline: 1.0013x; 1.0013x over previous
//
#include <hip/hip_runtime.h>
#include <hip/hip_bf16.h>

#define Df 384
#define Hf 768
#define SCAN_CH 4096

typedef __bf16 bf16x8 __attribute__((ext_vector_type(8)));
typedef float f32x4 __attribute__((ext_vector_type(4)));

struct __attribute__((aligned(4))) U12 { unsigned int x, y, z; };

__device__ inline unsigned short f2bf(float f) {
    __hip_bfloat16 h = __float2bfloat16(f);
    return __builtin_bit_cast(unsigned short, h);
}
__device__ inline float bf2f(unsigned short u) {
    unsigned int v = ((unsigned int)u) << 16;
    return __builtin_bit_cast(float, v);
}
__device__ inline float lobf(unsigned int v) { return bf2f((unsigned short)(v & 0xffff)); }
__device__ inline float hibf(unsigned int v) { return bf2f((unsigned short)(v >> 16)); }
__device__ inline unsigned int pk2(float a, float b) {
    return (unsigned int)f2bf(a) | ((unsigned int)f2bf(b) << 16);
}
__device__ inline float gelu_(float v) {
    return 0.5f * v * (1.0f + erff(v * 0.70710678118654752f));
}
// direct global->LDS, 16B per lane; LDS dest is wave-uniform base + lane*16,
// global source address is PER-LANE (used for the read-swizzle inverse).
__device__ inline void gload16(const void* g, void* l) {
    __builtin_amdgcn_global_load_lds(
        (const __attribute__((address_space(1))) unsigned int*)g,
        (__attribute__((address_space(3))) unsigned int*)l, 16, 0, 0);
}

// ---- BN column statistics: sum + sumsq per feature ----
__global__ void bn_stats(const float* __restrict__ x, float* __restrict__ stats, int N) {
    int t = threadIdx.x;                 // 192 threads
    int c4 = (t % 96) * 4;
    int rs = t / 96;
    float s0 = 0, s1 = 0, s2 = 0, s3 = 0, q0 = 0, q1 = 0, q2 = 0, q3 = 0;
    for (int r = blockIdx.x * 2 + rs; r < N; r += gridDim.x * 2) {
        float4 v = *(const float4*)(x + (size_t)r * Df + c4);
        s0 += v.x; s1 += v.y; s2 += v.z; s3 += v.w;
        q0 += v.x * v.x; q1 += v.y * v.y; q2 += v.z * v.z; q3 += v.w * v.w;
    }
    unsafeAtomicAdd(&stats[c4 + 0], s0);
    unsafeAtomicAdd(&stats[c4 + 1], s1);
    unsafeAtomicAdd(&stats[c4 + 2], s2);
    unsafeAtomicAdd(&stats[c4 + 3], s3);
    unsafeAtomicAdd(&stats[Df + c4 + 0], q0);
    unsafeAtomicAdd(&stats[Df + c4 + 1], q1);
    unsafeAtomicAdd(&stats[Df + c4 + 2], q2);
    unsafeAtomicAdd(&stats[Df + c4 + 3], q3);
}

__global__ void bn_finalize(const float* __restrict__ stats,
                            const float* __restrict__ gamma,
                            const float* __restrict__ beta,
                            float* __restrict__ coef, int N) {
    int c = threadIdx.x; // 384
    float invN = 1.0f / (float)N;
    float mu = stats[c] * invN;
    float var = stats[Df + c] * invN - mu * mu;
    float rs = rsqrtf(var + 1e-5f);
    float a = gamma[c] * rs;
    coef[c] = a;
    coef[Df + c] = beta[c] - mu * a;
}

// ---- h = x*a + b  ->  bf16 ----
__global__ void h_kernel(const float* __restrict__ x, const float* __restrict__ coef,
                         unsigned short* __restrict__ hb, int tot8) {
    int i = blockIdx.x * 256 + threadIdx.x;
    if (i >= tot8) return;
    size_t base = (size_t)i * 8;
    int c = (int)(base % Df);
    float4 x0 = *(const float4*)(x + base);
    float4 x1 = *(const float4*)(x + base + 4);
    const float* a = coef + c;
    const float* b = coef + Df + c;
    uint4 o;
    o.x = pk2(x0.x * a[0] + b[0], x0.y * a[1] + b[1]);
    o.y = pk2(x0.z * a[2] + b[2], x0.w * a[3] + b[3]);
    o.z = pk2(x1.x * a[4] + b[4], x1.y * a[5] + b[5]);
    o.w = pk2(x1.z * a[6] + b[6], x1.w * a[7] + b[7]);
    *(uint4*)(hb + base) = o;
}

// ---- weight transpose + cast: W[K][Nc] f32 -> Wt[Nc][K] bf16 ----
__global__ void wtrans(const float* __restrict__ Wsrc, unsigned short* __restrict__ Wdst,
                       int K, int Nc) {
    int idx = blockIdx.x * 256 + threadIdx.x;
    if (idx >= K * Nc) return;
    int k = idx / Nc, n = idx % Nc;
    Wdst[(size_t)n * K + k] = f2bf(Wsrc[idx]);
}

// ---- CSR build ----
__global__ void degree_k(const int* __restrict__ dst, int* __restrict__ deg, int E) {
    int e = blockIdx.x * 256 + threadIdx.x;
    if (e < E) atomicAdd(&deg[dst[e]], 1);
}

__global__ void scan1(const int* __restrict__ deg, int* __restrict__ off,
                      int* __restrict__ sums, int N) {
    __shared__ int ts[256];
    int t = threadIdx.x;
    int base = blockIdx.x * SCAN_CH + t * 16;
    int v[16];
    int s = 0;
    for (int j = 0; j < 16; j++) {
        int idx = base + j;
        int d = (idx < N) ? deg[idx] : 0;
        v[j] = s;
        s += d;
    }
    ts[t] = s;
    __syncthreads();
    for (int o = 1; o < 256; o <<= 1) {
        int add = (t >= o) ? ts[t - o] : 0;
        __syncthreads();
        ts[t] += add;
        __syncthreads();
    }
    int pre = t ? ts[t - 1] : 0;
    for (int j = 0; j < 16; j++) {
        int idx = base + j;
        if (idx < N) off[idx] = pre + v[j];
    }
    if (t == 255) sums[blockIdx.x] = ts[255];
}

__global__ void scan2(int* __restrict__ sums, int nb) {
    int acc = 0;
    for (int b = 0; b < nb; b++) { int v = sums[b]; sums[b] = acc; acc += v; }
    sums[nb] = acc;
}

__global__ void scan3(int* __restrict__ off, const int* __restrict__ sums, int N, int nb) {
    int idx = blockIdx.x * 256 + threadIdx.x;
    if (idx < N) off[idx] += sums[idx / SCAN_CH];
    else if (idx == N) off[N] = sums[nb];
}

// fill: pose[e] = CSR slot of edge e; srcp[slot] = src node of that edge
__global__ void fill_k(const int* __restrict__ dst, const int* __restrict__ src,
                       int* __restrict__ cursor, int* __restrict__ srcp,
                       int* __restrict__ pose, int E) {
    int e = blockIdx.x * 256 + threadIdx.x;
    if (e >= E) return;
    int pos = atomicAdd(&cursor[dst[e]], 1);
    srcp[pos] = src[e];
    pose[e] = pos;
}

// ---- gather-reduce: z[i] = (1+eps)*h[i] + sum_{p in [off[i],off[i+1])} relu(msgl[p] + h[srcp[p]]) ----
__global__ __launch_bounds__(256) void aggregate(
    const unsigned short* __restrict__ msgl, const unsigned short* __restrict__ hb,
    const int* __restrict__ off, const int* __restrict__ srcp,
    const float* __restrict__ epsp,
    unsigned short* __restrict__ zb, int N) {
    int lane = threadIdx.x & 63;
    int wid = threadIdx.x >> 6;
    int nwaves = gridDim.x * 4;
    float s1p = 1.0f + epsp[0];
    int loff = lane * 6;
    for (int i = blockIdx.x * 4 + wid; i < N; i += nwaves) {
        int o0 = off[i], o1 = off[i + 1];
        float a0 = 0, a1 = 0, a2 = 0, a3 = 0, a4 = 0, a5 = 0;
        for (int p = o0; p < o1; ++p) {
            int s = srcp[p];
            U12 mv = *(const U12*)(msgl + (size_t)p * Df + loff);
            U12 hv = *(const U12*)(hb + (size_t)s * Df + loff);
            a0 += fmaxf(lobf(mv.x) + lobf(hv.x), 0.f);
            a1 += fmaxf(hibf(mv.x) + hibf(hv.x), 0.f);
            a2 += fmaxf(lobf(mv.y) + lobf(hv.y), 0.f);
            a3 += fmaxf(hibf(mv.y) + hibf(hv.y), 0.f);
            a4 += fmaxf(lobf(mv.z) + lobf(hv.z), 0.f);
            a5 += fmaxf(hibf(mv.z) + hibf(hv.z), 0.f);
        }
        U12 hv = *(const U12*)(hb + (size_t)i * Df + loff);
        U12 o;
        o.x = pk2(s1p * lobf(hv.x) + a0, s1p * hibf(hv.x) + a1);
        o.y = pk2(s1p * lobf(hv.y) + a2, s1p * hibf(hv.y) + a3);
        o.z = pk2(s1p * lobf(hv.z) + a4, s1p * hibf(hv.z) + a5);
        *(U12*)(zb + (size_t)i * Df + loff) = o;
    }
}

// ---- B-resident GEMM: C = A @ Bt^T (+bias + epilogue) ----
// Block = 256 rows x 64 cols, 4 waves. B panel resident in LDS (once per
// 384-k chunk, swizzled source / swizzled read -> conflict-free).
// A streams global->REGISTERS with depth-D prefetch held in NAMED arrays
// (pf0/pf1/pf2) accessed only with compile-time indices -> stays in VGPRs
// (R6 bug: lambda pointer forced pf to scratch, VGPR_Count=68 was the tell).
// EPI 1: out = bf16(gelu(acc + bias))
// EPI 2: out = xres + gelu(acc + bias)   (f32)
// EPI 3: out row permuted via pose: outb[pose[row]] = bf16(acc + bias)
template <int NTK, int EPI, bool ABF16>
__global__ __launch_bounds__(256, 3) void gemm2(
    const void* __restrict__ Ap, const unsigned short* __restrict__ Bt,
    const float* __restrict__ bias, int M, int ncols,
    const int* __restrict__ pose,
    unsigned short* __restrict__ outb,
    const float* __restrict__ xres, float* __restrict__ outf, int ldo) {
    constexpr int K = NTK * 32;
    constexpr int NCH = (NTK + 11) / 12;   // 384-k chunks
    constexpr int CKT = NTK / NCH;         // kt per chunk (12)
    constexpr int D = ABF16 ? 3 : 2;       // A prefetch depth
    constexpr int PW = ABF16 ? 4 : 8;      // uint4 per prefetch stage
    __shared__ __align__(16) unsigned short Bs[CKT * 64 * 32];

    const int t = threadIdx.x;
    // m204 bijective XCD swizzle, col-block fastest within an XCD chunk
    const int nwg = gridDim.x;
    const int orig = blockIdx.x;
    const int xcd = orig & 7;
    const int q = nwg >> 3, r = nwg & 7;
    const int wgid = (xcd < r ? xcd * (q + 1) : r * (q + 1) + (xcd - r) * q) + (orig >> 3);
    const int pp = wgid / ncols;
    const int m0 = pp * 256;
    const int n0 = (wgid - pp * ncols) * 64;

    const int lane = t & 63;
    const int wid = t >> 6;
    const int fr = lane & 15;
    const int kg = lane >> 4;
    const int crow = lane >> 2;   // B-staging row within 16-row group
    const int cseg = lane & 3;    // B-staging 16B segment
    const int ssw = (crow >> 1) & 3;       // staging source swizzle
    const int bseg = kg ^ ((fr >> 1) & 3); // read-side swizzle (same involution)

    f32x4 acc[4][4];
#pragma unroll
    for (int i = 0; i < 4; i++)
#pragma unroll
        for (int j = 0; j < 4; j++) acc[i][j] = (f32x4){0.f, 0.f, 0.f, 0.f};

    int arow[4];
#pragma unroll
    for (int i = 0; i < 4; i++) {
        int rr = m0 + wid * 64 + i * 16 + fr;
        arow[i] = rr < M ? rr : M - 1;
    }

    auto stageB = [&](int ch) {
        const int ktw = wid * 3;
#pragma unroll
        for (int c = 0; c < 3; c++) {
#pragma unroll
            for (int rb = 0; rb < 64; rb += 16) {
                const int col = n0 + rb + crow;
                const int kk = (ch * CKT + ktw + c) * 32 + ((cseg ^ ssw) << 3);
                gload16(Bt + (size_t)col * K + kk,
                        &Bs[((ktw + c) * 64 + rb) * 32]);
            }
        }
    };

#define ISSUE_A(ktv, buf) do {                                                  \
        const int kA_ = (ktv);                                                  \
        _Pragma("unroll")                                                       \
        for (int i_ = 0; i_ < 4; i_++) {                                        \
            if constexpr (ABF16) {                                              \
                buf[i_] = *(const uint4*)((const unsigned short*)Ap +           \
                          (size_t)arow[i_] * K + kA_ * 32 + kg * 8);            \
            } else {                                                            \
                const float* p_ = (const float*)Ap +                            \
                          (size_t)arow[i_] * K + kA_ * 32 + kg * 8;             \
                buf[2 * i_] = *(const uint4*)p_;                                \
                buf[2 * i_ + 1] = *(const uint4*)(p_ + 4);                      \
            }                                                                   \
        }                                                                       \
    } while (0)

#define KT_STEP(ktv, buf) do {                                                  \
        const int kT_ = (ktv);                                                  \
        bf16x8 bfr[4];                                                          \
        _Pragma("unroll")                                                       \
        for (int j_ = 0; j_ < 4; j_++)                                          \
            bfr[j_] = *(const bf16x8*)((const char*)Bs +                        \
                      ((((kT_) % CKT) * 64 + j_ * 16 + fr) * 64 + bseg * 16));  \
        bf16x8 afr[4];                                                          \
        _Pragma("unroll")                                                       \
        for (int i_ = 0; i_ < 4; i_++) {                                        \
            if constexpr (ABF16) {                                              \
                afr[i_] = __builtin_bit_cast(bf16x8, buf[i_]);                  \
            } else {                                                            \
                float4 x0_ = __builtin_bit_cast(float4, buf[2 * i_]);           \
                float4 x1_ = __builtin_bit_cast(float4, buf[2 * i_ + 1]);       \
                uint4 u_;                                                       \
                u_.x = pk2(x0_.x, x0_.y); u_.y = pk2(x0_.z, x0_.w);             \
                u_.z = pk2(x1_.x, x1_.y); u_.w = pk2(x1_.z, x1_.w);             \
                afr[i_] = __builtin_bit_cast(bf16x8, u_);                       \
            }                                                                   \
        }                                                                       \
        if (kT_ + D < NTK) ISSUE_A(kT_ + D, buf);                               \
        _Pragma("unroll")                                                       \
        for (int i_ = 0; i_ < 4; i_++)                                          \
            _Pragma("unroll")                                                   \
            for (int j_ = 0; j_ < 4; j_++)                                      \
                acc[i_][j_] = __builtin_amdgcn_mfma_f32_16x16x32_bf16(          \
                    afr[i_], bfr[j_], acc[i_][j_], 0, 0, 0);                    \
    } while (0)

    uint4 pf0[PW], pf1[PW], pf2[PW];
    stageB(0);
    ISSUE_A(0, pf0);
    ISSUE_A(1, pf1);
    if constexpr (D == 3) ISSUE_A(2, pf2);
    __syncthreads();   // B chunk 0 ready (vmcnt drain)

#pragma unroll
    for (int ch = 0; ch < NCH; ch++) {
        if (ch > 0) {
            __syncthreads();      // everyone done reading previous chunk
            stageB(ch);
            __syncthreads();      // new chunk ready
        }
#pragma unroll
        for (int k = 0; k < CKT; k += D) {
            KT_STEP(ch * CKT + k, pf0);
            KT_STEP(ch * CKT + k + 1, pf1);
            if constexpr (D == 3) KT_STEP(ch * CKT + k + 2, pf2);
        }
    }
#undef KT_STEP
#undef ISSUE_A

    float bi[4];
#pragma unroll
    for (int j = 0; j < 4; j++) bi[j] = bias[n0 + j * 16 + fr];

    const int kg4 = kg * 4;
#pragma unroll
    for (int i = 0; i < 4; i++) {
        const int rb = m0 + wid * 64 + i * 16 + kg4;
#pragma unroll
        for (int j = 0; j < 4; j++) {
            const int c = n0 + j * 16 + fr;
#pragma unroll
            for (int r = 0; r < 4; r++) {
                const int row = rb + r;
                if (row < M) {
                    float v = acc[i][j][r] + bi[j];
                    if (EPI == 1) {
                        outb[(size_t)row * ldo + c] = f2bf(gelu_(v));
                    } else if (EPI == 2) {
                        size_t o = (size_t)row * ldo + c;
                        outf[o] = xres[o] + gelu_(v);
                    } else {
                        outb[(size_t)pose[row] * ldo + c] = f2bf(v);
                    }
                }
            }
        }
    }
}

extern "C" void kernel_launch(void* const* d_in, const int* in_sizes, int n_in,
                              void* d_out, int out_size, void* d_ws, size_t ws_size,
                              hipStream_t stream) {
    const float* x = (const float*)d_in[0];
    const float* ea = (const float*)d_in[1];
    const float* gamma = (const float*)d_in[2];
    const float* beta = (const float*)d_in[3];
    const float* epsp = (const float*)d_in[4];
    const float* W_edge = (const float*)d_in[5];
    const float* b_edge = (const float*)d_in[6];
    const float* W1 = (const float*)d_in[7];
    const float* b1 = (const float*)d_in[8];
    const float* W2 = (const float*)d_in[9];
    const float* b2 = (const float*)d_in[10];
    const int* eidx = (const int*)d_in[11];
    float* out = (float*)d_out;
    const int N = in_sizes[0] / Df;
    const int E = in_sizes[1] / Df;
    const int* esrc = eidx;
    const int* edst = eidx + E;

    char* w = (char*)d_ws;
    size_t off_ = 0;
    auto alloc = [&](size_t bytes) { char* p = w + off_; off_ += (bytes + 255) & ~(size_t)255; return p; };
    float* stats = (float*)alloc(2 * Df * sizeof(float));
    float* coef = (float*)alloc(2 * Df * sizeof(float));
    unsigned short* hb = (unsigned short*)alloc((size_t)N * Df * 2);
    unsigned short* zb = (unsigned short*)alloc((size_t)N * Df * 2);
    unsigned short* tb = (unsigned short*)alloc((size_t)N * Hf * 2);
    unsigned short* WeT = (unsigned short*)alloc((size_t)Df * Df * 2);
    unsigned short* W1T = (unsigned short*)alloc((size_t)Df * Hf * 2);
    unsigned short* W2T = (unsigned short*)alloc((size_t)Hf * Df * 2);
    int* deg = (int*)alloc((size_t)(N + 1) * 4);      // reused as fill cursor
    int* offs = (int*)alloc((size_t)(N + 1) * 4);
    int* srcp = (int*)alloc((size_t)E * 4);
    int* pose = (int*)alloc((size_t)E * 4);
    int* sums = (int*)alloc(64 * 4);
    size_t msgl_bytes = (size_t)E * Df * 2;
    unsigned short* msgl;
    if (off_ + msgl_bytes <= ws_size) msgl = (unsigned short*)alloc(msgl_bytes);
    else msgl = (unsigned short*)d_out;   // dead until final GEMM writes it
    (void)n_in; (void)out_size;

    hipMemsetAsync(stats, 0, 2 * Df * sizeof(float), stream);
    hipMemsetAsync(deg, 0, (size_t)N * 4, stream);

    // BN + h
    bn_stats<<<1024, 192, 0, stream>>>(x, stats, N);
    bn_finalize<<<1, Df, 0, stream>>>(stats, gamma, beta, coef, N);
    int tot8 = N * Df / 8;
    h_kernel<<<(tot8 + 255) / 256, 256, 0, stream>>>(x, coef, hb, tot8);

    // weights
    wtrans<<<(Df * Df + 255) / 256, 256, 0, stream>>>(W_edge, WeT, Df, Df);
    wtrans<<<(Df * Hf + 255) / 256, 256, 0, stream>>>(W1, W1T, Df, Hf);
    wtrans<<<(Hf * Df + 255) / 256, 256, 0, stream>>>(W2, W2T, Hf, Df);

    // CSR by dst
    int nb = (N + SCAN_CH - 1) / SCAN_CH;
    degree_k<<<(E + 255) / 256, 256, 0, stream>>>(edst, deg, E);
    scan1<<<nb, 256, 0, stream>>>(deg, offs, sums, N);
    scan2<<<1, 1, 0, stream>>>(sums, nb);
    scan3<<<(N + 256) / 256, 256, 0, stream>>>(offs, sums, N, nb);
    hipMemcpyAsync(deg, offs, (size_t)N * 4, hipMemcpyDeviceToDevice, stream);
    fill_k<<<(E + 255) / 256, 256, 0, stream>>>(edst, esrc, deg, srcp, pose, E);

    // edge linear: msgl[pose[e]] = ea[e] @ We^T + b_edge  (bf16, CSR-ordered)
    int ep2 = (E + 255) / 256;
    gemm2<12, 3, false><<<dim3(ep2 * (Df / 64)), 256, 0, stream>>>(
        ea, WeT, b_edge, E, Df / 64, pose, msgl, nullptr, nullptr, Df);

    // gather-reduce -> z (bf16)
    aggregate<<<2048, 256, 0, stream>>>(msgl, hb, offs, srcp, epsp, zb, N);

    // MLP
    int np2 = (N + 255) / 256;
    gemm2<12, 1, true><<<dim3(np2 * (Hf / 64)), 256, 0, stream>>>(
        zb, W1T, b1, N, Hf / 64, nullptr, tb, nullptr, nullptr, Hf);
    gemm2<24, 2, true><<<dim3(np2 * (Df / 64)), 256, 0, stream>>>(
        tb, W2T, b2, N, Df / 64, nullptr, nullptr, x, out, Df);
}

// Round 8
// 1121.396 us; speedup vs baseline: 1.0824x; 1.0810x over previous
//
#include <hip/hip_runtime.h>
#include <hip/hip_bf16.h>

#define Df 384
#define Hf 768
#define SCAN_CH 4096

typedef __bf16 bf16x8 __attribute__((ext_vector_type(8)));
typedef float f32x4 __attribute__((ext_vector_type(4)));

struct __attribute__((aligned(4))) U12 { unsigned int x, y, z; };

__device__ inline unsigned short f2bf(float f) {
    __hip_bfloat16 h = __float2bfloat16(f);
    return __builtin_bit_cast(unsigned short, h);
}
__device__ inline float bf2f(unsigned short u) {
    unsigned int v = ((unsigned int)u) << 16;
    return __builtin_bit_cast(float, v);
}
__device__ inline float lobf(unsigned int v) { return bf2f((unsigned short)(v & 0xffff)); }
__device__ inline float hibf(unsigned int v) { return bf2f((unsigned short)(v >> 16)); }
__device__ inline unsigned int pk2(float a, float b) {
    return (unsigned int)f2bf(a) | ((unsigned int)f2bf(b) << 16);
}
__device__ inline float gelu_(float v) {
    return 0.5f * v * (1.0f + erff(v * 0.70710678118654752f));
}
// direct global->LDS, 16B per lane; LDS dest is WAVE-UNIFORM base, HW adds lane*16.
__device__ inline void gload16(const void* g, void* l) {
    __builtin_amdgcn_global_load_lds(
        (const __attribute__((address_space(1))) unsigned int*)g,
        (__attribute__((address_space(3))) unsigned int*)l, 16, 0, 0);
}

// ---- BN column statistics ----
__global__ void bn_stats(const float* __restrict__ x, float* __restrict__ stats, int N) {
    int t = threadIdx.x;                 // 192 threads
    int c4 = (t % 96) * 4;
    int rs = t / 96;
    float s0 = 0, s1 = 0, s2 = 0, s3 = 0, q0 = 0, q1 = 0, q2 = 0, q3 = 0;
    for (int r = blockIdx.x * 2 + rs; r < N; r += gridDim.x * 2) {
        float4 v = *(const float4*)(x + (size_t)r * Df + c4);
        s0 += v.x; s1 += v.y; s2 += v.z; s3 += v.w;
        q0 += v.x * v.x; q1 += v.y * v.y; q2 += v.z * v.z; q3 += v.w * v.w;
    }
    unsafeAtomicAdd(&stats[c4 + 0], s0);
    unsafeAtomicAdd(&stats[c4 + 1], s1);
    unsafeAtomicAdd(&stats[c4 + 2], s2);
    unsafeAtomicAdd(&stats[c4 + 3], s3);
    unsafeAtomicAdd(&stats[Df + c4 + 0], q0);
    unsafeAtomicAdd(&stats[Df + c4 + 1], q1);
    unsafeAtomicAdd(&stats[Df + c4 + 2], q2);
    unsafeAtomicAdd(&stats[Df + c4 + 3], q3);
}

__global__ void bn_finalize(const float* __restrict__ stats,
                            const float* __restrict__ gamma,
                            const float* __restrict__ beta,
                            float* __restrict__ coef, int N) {
    int c = threadIdx.x; // 384
    float invN = 1.0f / (float)N;
    float mu = stats[c] * invN;
    float var = stats[Df + c] * invN - mu * mu;
    float rs = rsqrtf(var + 1e-5f);
    float a = gamma[c] * rs;
    coef[c] = a;
    coef[Df + c] = beta[c] - mu * a;
}

// ---- h = x*a + b  ->  bf16 ----
__global__ void h_kernel(const float* __restrict__ x, const float* __restrict__ coef,
                         unsigned short* __restrict__ hb, int tot8) {
    int i = blockIdx.x * 256 + threadIdx.x;
    if (i >= tot8) return;
    size_t base = (size_t)i * 8;
    int c = (int)(base % Df);
    float4 x0 = *(const float4*)(x + base);
    float4 x1 = *(const float4*)(x + base + 4);
    const float* a = coef + c;
    const float* b = coef + Df + c;
    uint4 o;
    o.x = pk2(x0.x * a[0] + b[0], x0.y * a[1] + b[1]);
    o.y = pk2(x0.z * a[2] + b[2], x0.w * a[3] + b[3]);
    o.z = pk2(x1.x * a[4] + b[4], x1.y * a[5] + b[5]);
    o.w = pk2(x1.z * a[6] + b[6], x1.w * a[7] + b[7]);
    *(uint4*)(hb + base) = o;
}

// ---- plain f32 -> bf16 cast (for ea) ----
__global__ void cast_bf16(const float* __restrict__ src, unsigned short* __restrict__ dst, int tot8) {
    int i = blockIdx.x * 256 + threadIdx.x;
    if (i >= tot8) return;
    size_t base = (size_t)i * 8;
    float4 x0 = *(const float4*)(src + base);
    float4 x1 = *(const float4*)(src + base + 4);
    uint4 o;
    o.x = pk2(x0.x, x0.y); o.y = pk2(x0.z, x0.w);
    o.z = pk2(x1.x, x1.y); o.w = pk2(x1.z, x1.w);
    *(uint4*)(dst + base) = o;
}

// ---- weight transpose + cast: W[K][Nc] f32 -> Wt[Nc][K] bf16 ----
__global__ void wtrans(const float* __restrict__ Wsrc, unsigned short* __restrict__ Wdst,
                       int K, int Nc) {
    int idx = blockIdx.x * 256 + threadIdx.x;
    if (idx >= K * Nc) return;
    int k = idx / Nc, n = idx % Nc;
    Wdst[(size_t)n * K + k] = f2bf(Wsrc[idx]);
}

// ---- CSR build ----
__global__ void degree_k(const int* __restrict__ dst, int* __restrict__ deg, int E) {
    int e = blockIdx.x * 256 + threadIdx.x;
    if (e < E) atomicAdd(&deg[dst[e]], 1);
}

__global__ void scan1(const int* __restrict__ deg, int* __restrict__ off,
                      int* __restrict__ sums, int N) {
    __shared__ int ts[256];
    int t = threadIdx.x;
    int base = blockIdx.x * SCAN_CH + t * 16;
    int v[16];
    int s = 0;
    for (int j = 0; j < 16; j++) {
        int idx = base + j;
        int d = (idx < N) ? deg[idx] : 0;
        v[j] = s;
        s += d;
    }
    ts[t] = s;
    __syncthreads();
    for (int o = 1; o < 256; o <<= 1) {
        int add = (t >= o) ? ts[t - o] : 0;
        __syncthreads();
        ts[t] += add;
        __syncthreads();
    }
    int pre = t ? ts[t - 1] : 0;
    for (int j = 0; j < 16; j++) {
        int idx = base + j;
        if (idx < N) off[idx] = pre + v[j];
    }
    if (t == 255) sums[blockIdx.x] = ts[255];
}

__global__ void scan2(int* __restrict__ sums, int nb) {
    int acc = 0;
    for (int b = 0; b < nb; b++) { int v = sums[b]; sums[b] = acc; acc += v; }
    sums[nb] = acc;
}

__global__ void scan3(int* __restrict__ off, const int* __restrict__ sums, int N, int nb) {
    int idx = blockIdx.x * 256 + threadIdx.x;
    if (idx < N) off[idx] += sums[idx / SCAN_CH];
    else if (idx == N) off[N] = sums[nb];
}

// fill: pose[e] = CSR slot of edge e; srcp[slot] = src node of that edge
__global__ void fill_k(const int* __restrict__ dst, const int* __restrict__ src,
                       int* __restrict__ cursor, int* __restrict__ srcp,
                       int* __restrict__ pose, int E) {
    int e = blockIdx.x * 256 + threadIdx.x;
    if (e >= E) return;
    int pos = atomicAdd(&cursor[dst[e]], 1);
    srcp[pos] = src[e];
    pose[e] = pos;
}

// ---- gather-reduce: z[i] = (1+eps)*h[i] + sum relu(msgl[p] + h[srcp[p]]) ----
__global__ __launch_bounds__(256) void aggregate(
    const unsigned short* __restrict__ msgl, const unsigned short* __restrict__ hb,
    const int* __restrict__ off, const int* __restrict__ srcp,
    const float* __restrict__ epsp,
    unsigned short* __restrict__ zb, int N) {
    int lane = threadIdx.x & 63;
    int wid = threadIdx.x >> 6;
    int nwaves = gridDim.x * 4;
    float s1p = 1.0f + epsp[0];
    int loff = lane * 6;
    for (int i = blockIdx.x * 4 + wid; i < N; i += nwaves) {
        int o0 = off[i], o1 = off[i + 1];
        float a0 = 0, a1 = 0, a2 = 0, a3 = 0, a4 = 0, a5 = 0;
        for (int p = o0; p < o1; ++p) {
            int s = srcp[p];
            U12 mv = *(const U12*)(msgl + (size_t)p * Df + loff);
            U12 hv = *(const U12*)(hb + (size_t)s * Df + loff);
            a0 += fmaxf(lobf(mv.x) + lobf(hv.x), 0.f);
            a1 += fmaxf(hibf(mv.x) + hibf(hv.x), 0.f);
            a2 += fmaxf(lobf(mv.y) + lobf(hv.y), 0.f);
            a3 += fmaxf(hibf(mv.y) + hibf(hv.y), 0.f);
            a4 += fmaxf(lobf(mv.z) + lobf(hv.z), 0.f);
            a5 += fmaxf(hibf(mv.z) + hibf(hv.z), 0.f);
        }
        U12 hv = *(const U12*)(hb + (size_t)i * Df + loff);
        U12 o;
        o.x = pk2(s1p * lobf(hv.x) + a0, s1p * hibf(hv.x) + a1);
        o.y = pk2(s1p * lobf(hv.y) + a2, s1p * hibf(hv.y) + a3);
        o.z = pk2(s1p * lobf(hv.z) + a4, s1p * hibf(hv.z) + a5);
        *(U12*)(zb + (size_t)i * Df + loff) = o;
    }
}

// ---- Triple-buffered counted-vmcnt GEMM: C = A @ Bt^T (+bias + epilogue) ----
// BM=256, BN=128, BK=64. 512 threads = 8 waves (4M x 2N), wave owns 64x64.
// LDS: 3 buffers (A 32KB + B 16KB each) = 144KB -> 1 block/CU.
// Staging: global_load_lds, linear dest, PRE-SWIZZLED source col16^(row&7);
// reads use the same XOR -> <=2-way banks (free). Tile t+2's 6 loads/thread
// are issued spread through tile t's compute; end-of-tile sync is
// s_waitcnt vmcnt(6) + raw s_barrier (counted -- never drains the pipeline).
// EPI 1: out = bf16(gelu(acc+bias)); EPI 2: out = xres + gelu(acc+bias) (f32);
// EPI 3: outb[pose[row]] = bf16(acc+bias)
template <int NT, int EPI>
__global__ __launch_bounds__(512, 1) void gemm8(
    const unsigned short* __restrict__ Ab, const unsigned short* __restrict__ Bt,
    const float* __restrict__ bias, int M, int ncols,
    const int* __restrict__ pose,
    unsigned short* __restrict__ outb,
    const float* __restrict__ xres, float* __restrict__ outf, int ldo) {
    constexpr int K = NT * 64;
    __shared__ __align__(16) unsigned short As[3 * 256 * 64];
    __shared__ __align__(16) unsigned short Bs[3 * 128 * 64];

    const int t = threadIdx.x;
    // m204 bijective XCD swizzle, col-block fastest within an XCD chunk
    const int nwg = gridDim.x;
    const int orig = blockIdx.x;
    const int xcd = orig & 7;
    const int q = nwg >> 3, r = nwg & 7;
    const int wgid = (xcd < r ? xcd * (q + 1) : r * (q + 1) + (xcd - r) * q) + (orig >> 3);
    const int pp = wgid / ncols;
    const int m0 = pp * 256;
    const int n0 = (wgid - pp * ncols) * 128;

    const int lane = t & 63;
    const int wid = t >> 6;
    const int fr = lane & 15;
    const int kg = lane >> 4;
    const int wm = wid >> 1;       // 0..3 (64-row slice)
    const int wn = wid & 1;        // 0..1 (64-col slice)
    const int srow = lane >> 3;            // staging row within wave's 8-row slice
    const int scol = (lane & 7) ^ srow;    // pre-swizzled source col16

    f32x4 acc[4][4];
#pragma unroll
    for (int i = 0; i < 4; i++)
#pragma unroll
        for (int j = 0; j < 4; j++) acc[i][j] = (f32x4){0.f, 0.f, 0.f, 0.f};

    // ---- staging helpers (dst is wave-uniform; HW adds lane*16) ----
#define STG_A(u, kt_, bufi) do {                                                \
        int rr_ = m0 + (u) * 64 + wid * 8 + srow;                               \
        if (rr_ >= M) rr_ = M - 1;                                              \
        gload16(Ab + (size_t)rr_ * K + (kt_) * 64 + (scol << 3),                \
                &As[(bufi) * 16384 + (u) * 4096 + wid * 512]);                  \
    } while (0)
#define STG_B(u, kt_, bufi) do {                                                \
        int rr_ = n0 + (u) * 64 + wid * 8 + srow;                               \
        gload16(Bt + (size_t)rr_ * K + (kt_) * 64 + (scol << 3),                \
                &Bs[(bufi) * 8192 + (u) * 4096 + wid * 512]);                   \
    } while (0)

    // prologue: stage tiles 0 and 1
#pragma unroll
    for (int u = 0; u < 4; u++) STG_A(u, 0, 0);
    STG_B(0, 0, 0); STG_B(1, 0, 0);
#pragma unroll
    for (int u = 0; u < 4; u++) STG_A(u, 1, 1);
    STG_B(0, 1, 1); STG_B(1, 1, 1);
    asm volatile("s_waitcnt vmcnt(6)" ::: "memory");   // tile 0 ready, tile 1 in flight
    __builtin_amdgcn_s_barrier();
    asm volatile("" ::: "memory");

    for (int kt = 0; kt < NT; ++kt) {
        const unsigned short* Ac = As + (kt % 3) * 16384;
        const unsigned short* Bc = Bs + (kt % 3) * 8192;
        const int nb = (kt + 2) % 3;
        const bool st = (kt + 2) < NT;

        if (st) { STG_A(0, kt + 2, nb); STG_A(1, kt + 2, nb); }

        bf16x8 a[4], b[4];
        // ks = 0 fragments (k-chunk col16 = kg)
#pragma unroll
        for (int i = 0; i < 4; i++) {
            const int row = wm * 64 + i * 16 + fr;
            a[i] = *(const bf16x8*)&Ac[row * 64 + ((kg ^ (row & 7)) << 3)];
        }
#pragma unroll
        for (int j = 0; j < 4; j++) {
            const int row = wn * 64 + j * 16 + fr;
            b[j] = *(const bf16x8*)&Bc[row * 64 + ((kg ^ (row & 7)) << 3)];
        }
        if (st) { STG_A(2, kt + 2, nb); STG_A(3, kt + 2, nb); }
        __builtin_amdgcn_s_setprio(1);
#pragma unroll
        for (int i = 0; i < 4; i++)
#pragma unroll
            for (int j = 0; j < 4; j++)
                acc[i][j] = __builtin_amdgcn_mfma_f32_16x16x32_bf16(a[i], b[j], acc[i][j], 0, 0, 0);
        __builtin_amdgcn_s_setprio(0);

        if (st) { STG_B(0, kt + 2, nb); STG_B(1, kt + 2, nb); }
        // ks = 1 fragments (k-chunk col16 = 4 + kg)
#pragma unroll
        for (int i = 0; i < 4; i++) {
            const int row = wm * 64 + i * 16 + fr;
            a[i] = *(const bf16x8*)&Ac[row * 64 + (((4 + kg) ^ (row & 7)) << 3)];
        }
#pragma unroll
        for (int j = 0; j < 4; j++) {
            const int row = wn * 64 + j * 16 + fr;
            b[j] = *(const bf16x8*)&Bc[row * 64 + (((4 + kg) ^ (row & 7)) << 3)];
        }
        __builtin_amdgcn_s_setprio(1);
#pragma unroll
        for (int i = 0; i < 4; i++)
#pragma unroll
            for (int j = 0; j < 4; j++)
                acc[i][j] = __builtin_amdgcn_mfma_f32_16x16x32_bf16(a[i], b[j], acc[i][j], 0, 0, 0);
        __builtin_amdgcn_s_setprio(0);

        if (kt < NT - 1) {
            if (st) asm volatile("s_waitcnt vmcnt(6)" ::: "memory");  // next tile ready; t+2 stays in flight
            else    asm volatile("s_waitcnt vmcnt(0)" ::: "memory");  // drain for final tiles
            __builtin_amdgcn_s_barrier();
            asm volatile("" ::: "memory");
        }
    }
#undef STG_A
#undef STG_B

    float bi[4];
#pragma unroll
    for (int j = 0; j < 4; j++) bi[j] = bias[n0 + wn * 64 + j * 16 + fr];

    const int kg4 = kg * 4;
#pragma unroll
    for (int i = 0; i < 4; i++) {
        const int rb = m0 + wm * 64 + i * 16 + kg4;
#pragma unroll
        for (int j = 0; j < 4; j++) {
            const int c = n0 + wn * 64 + j * 16 + fr;
#pragma unroll
            for (int r = 0; r < 4; r++) {
                const int row = rb + r;
                if (row < M) {
                    float v = acc[i][j][r] + bi[j];
                    if (EPI == 1) {
                        outb[(size_t)row * ldo + c] = f2bf(gelu_(v));
                    } else if (EPI == 2) {
                        size_t o = (size_t)row * ldo + c;
                        outf[o] = xres[o] + gelu_(v);
                    } else {
                        outb[(size_t)pose[row] * ldo + c] = f2bf(v);
                    }
                }
            }
        }
    }
}

extern "C" void kernel_launch(void* const* d_in, const int* in_sizes, int n_in,
                              void* d_out, int out_size, void* d_ws, size_t ws_size,
                              hipStream_t stream) {
    const float* x = (const float*)d_in[0];
    const float* ea = (const float*)d_in[1];
    const float* gamma = (const float*)d_in[2];
    const float* beta = (const float*)d_in[3];
    const float* epsp = (const float*)d_in[4];
    const float* W_edge = (const float*)d_in[5];
    const float* b_edge = (const float*)d_in[6];
    const float* W1 = (const float*)d_in[7];
    const float* b1 = (const float*)d_in[8];
    const float* W2 = (const float*)d_in[9];
    const float* b2 = (const float*)d_in[10];
    const int* eidx = (const int*)d_in[11];
    float* out = (float*)d_out;
    const int N = in_sizes[0] / Df;
    const int E = in_sizes[1] / Df;
    const int* esrc = eidx;
    const int* edst = eidx + E;

    char* w = (char*)d_ws;
    size_t off_ = 0;
    auto alloc = [&](size_t bytes) { char* p = w + off_; off_ += (bytes + 255) & ~(size_t)255; return p; };
    float* stats = (float*)alloc(2 * Df * sizeof(float));
    float* coef = (float*)alloc(2 * Df * sizeof(float));
    unsigned short* hb = (unsigned short*)alloc((size_t)N * Df * 2);
    unsigned short* zb = (unsigned short*)alloc((size_t)N * Df * 2);
    unsigned short* tb = (unsigned short*)alloc((size_t)N * Hf * 2);   // also hosts eab (dead before GEMM1)
    unsigned short* WeT = (unsigned short*)alloc((size_t)Df * Df * 2);
    unsigned short* W1T = (unsigned short*)alloc((size_t)Df * Hf * 2);
    unsigned short* W2T = (unsigned short*)alloc((size_t)Hf * Df * 2);
    int* deg = (int*)alloc((size_t)(N + 1) * 4);      // reused as fill cursor
    int* offs = (int*)alloc((size_t)(N + 1) * 4);
    int* srcp = (int*)alloc((size_t)E * 4);
    int* pose = (int*)alloc((size_t)E * 4);
    int* sums = (int*)alloc(64 * 4);
    size_t msgl_bytes = (size_t)E * Df * 2;
    unsigned short* msgl;
    if (off_ + msgl_bytes <= ws_size) msgl = (unsigned short*)alloc(msgl_bytes);
    else msgl = (unsigned short*)d_out;   // dead until final GEMM writes it
    unsigned short* eab = tb;             // ea as bf16, aliased onto tb
    (void)n_in; (void)out_size;

    hipMemsetAsync(stats, 0, 2 * Df * sizeof(float), stream);
    hipMemsetAsync(deg, 0, (size_t)N * 4, stream);

    // BN + h
    bn_stats<<<1024, 192, 0, stream>>>(x, stats, N);
    bn_finalize<<<1, Df, 0, stream>>>(stats, gamma, beta, coef, N);
    int tot8 = N * Df / 8;
    h_kernel<<<(tot8 + 255) / 256, 256, 0, stream>>>(x, coef, hb, tot8);

    // ea -> bf16
    int etot8 = E * Df / 8;
    cast_bf16<<<(etot8 + 255) / 256, 256, 0, stream>>>(ea, eab, etot8);

    // weights
    wtrans<<<(Df * Df + 255) / 256, 256, 0, stream>>>(W_edge, WeT, Df, Df);
    wtrans<<<(Df * Hf + 255) / 256, 256, 0, stream>>>(W1, W1T, Df, Hf);
    wtrans<<<(Hf * Df + 255) / 256, 256, 0, stream>>>(W2, W2T, Hf, Df);

    // CSR by dst
    int nb = (N + SCAN_CH - 1) / SCAN_CH;
    degree_k<<<(E + 255) / 256, 256, 0, stream>>>(edst, deg, E);
    scan1<<<nb, 256, 0, stream>>>(deg, offs, sums, N);
    scan2<<<1, 1, 0, stream>>>(sums, nb);
    scan3<<<(N + 256) / 256, 256, 0, stream>>>(offs, sums, N, nb);
    hipMemcpyAsync(deg, offs, (size_t)N * 4, hipMemcpyDeviceToDevice, stream);
    fill_k<<<(E + 255) / 256, 256, 0, stream>>>(edst, esrc, deg, srcp, pose, E);

    // edge linear: msgl[pose[e]] = eab[e] @ We^T + b_edge  (bf16, CSR-ordered)
    int ep = (E + 255) / 256;
    gemm8<6, 3><<<dim3(ep * (Df / 128)), 512, 0, stream>>>(
        eab, WeT, b_edge, E, Df / 128, pose, msgl, nullptr, nullptr, Df);

    // gather-reduce -> z (bf16)
    aggregate<<<2048, 256, 0, stream>>>(msgl, hb, offs, srcp, epsp, zb, N);

    // MLP
    int np = (N + 255) / 256;
    gemm8<6, 1><<<dim3(np * (Hf / 128)), 512, 0, stream>>>(
        zb, W1T, b1, N, Hf / 128, nullptr, tb, nullptr, nullptr, Hf);
    gemm8<12, 2><<<dim3(np * (Df / 128)), 512, 0, stream>>>(
        tb, W2T, b2, N, Df / 128, nullptr, nullptr, x, out, Df);
}